// Round 4
// baseline (1074.530 us; speedup 1.0000x reference)
//
#include <hip/hip_runtime.h>

#define N_TOK 3136   // 56*56
#define WOUT 56
#define HIN 112
#define WIN 112
#define CH 512
#define QKV_ROWS 1536
#define HEADS 8
#define HD 64

// ---------------- downsample: x (2,512,112,112) -> xds (2,512,3136) ----------------
__global__ __launch_bounds__(256) void k_downsample(const float* __restrict__ x,
                                                    float* __restrict__ xds) {
    int idx = blockIdx.x * 256 + threadIdx.x;   // total = 2*512*3136 = 12544*256 exactly
    int n  = idx % N_TOK;
    int bc = idx / N_TOK;
    int hh = n / WOUT, ww = n - hh * WOUT;
    xds[idx] = x[(size_t)bc * (HIN * WIN) + (size_t)(hh * 2) * WIN + ww * 2];
}

// ---------------- QKV GEMM: qkv[b,o,n] = sum_c w[o,c] * xds[b,c,n] ----------------
// 64x64 tile, BK=16, 256 threads, 4x4 per thread, fp32
__global__ __launch_bounds__(256) void k_qkv_gemm(const float* __restrict__ w,
                                                  const float* __restrict__ xds,
                                                  float* __restrict__ qkv) {
    __shared__ float As[16][64];   // As[kk][o] (transposed w tile)
    __shared__ float Bs[16][64];   // Bs[kk][n]
    const int t  = threadIdx.x;
    const int tx = t & 15, ty = t >> 4;
    const int n0 = blockIdx.x * 64;
    const int o0 = blockIdx.y * 64;
    const int b  = blockIdx.z;
    const float* Bbase = xds + (size_t)b * CH * N_TOK;

    float acc[4][4] = {};
    const int ao = t >> 2, aq = t & 3;         // A tile load: row o=ao, quad aq
    const int bk = t >> 4, bj = (t & 15) * 4;  // B tile load: row kk=bk, col bj

    for (int k0 = 0; k0 < CH; k0 += 16) {
        float4 av = *(const float4*)&w[(size_t)(o0 + ao) * CH + k0 + aq * 4];
        float4 bv = *(const float4*)&Bbase[(size_t)(k0 + bk) * N_TOK + n0 + bj];
        __syncthreads();   // previous iteration's reads done before overwrite
        As[aq * 4 + 0][ao] = av.x;
        As[aq * 4 + 1][ao] = av.y;
        As[aq * 4 + 2][ao] = av.z;
        As[aq * 4 + 3][ao] = av.w;
        *(float4*)&Bs[bk][bj] = bv;
        __syncthreads();
        #pragma unroll
        for (int kk = 0; kk < 16; ++kk) {
            float4 a  = *(const float4*)&As[kk][ty * 4];
            float4 bq = *(const float4*)&Bs[kk][tx * 4];
            acc[0][0] += a.x * bq.x; acc[0][1] += a.x * bq.y; acc[0][2] += a.x * bq.z; acc[0][3] += a.x * bq.w;
            acc[1][0] += a.y * bq.x; acc[1][1] += a.y * bq.y; acc[1][2] += a.y * bq.z; acc[1][3] += a.y * bq.w;
            acc[2][0] += a.z * bq.x; acc[2][1] += a.z * bq.y; acc[2][2] += a.z * bq.z; acc[2][3] += a.z * bq.w;
            acc[3][0] += a.w * bq.x; acc[3][1] += a.w * bq.y; acc[3][2] += a.w * bq.z; acc[3][3] += a.w * bq.w;
        }
    }
    #pragma unroll
    for (int ii = 0; ii < 4; ++ii) {
        float4 v = make_float4(acc[ii][0], acc[ii][1], acc[ii][2], acc[ii][3]);
        *(float4*)&qkv[((size_t)b * QKV_ROWS + o0 + ty * 4 + ii) * N_TOK + n0 + tx * 4] = v;
    }
}

// ---------------- flash attention, fp32, 64-query tiles, 64-key tiles ----------------
// out[(b*512 + h*64 + d), m] = sum_n softmax_n(q[:,m].k[:,n]) * v[d,n]
__global__ __launch_bounds__(256) void k_attn(const float* __restrict__ qkv,
                                              float* __restrict__ out) {
    __shared__ float Qs[64 * 64];  // [d][i]
    __shared__ float Ks[64 * 64];  // [d][j]
    __shared__ float Vs[64 * 64];  // [d][jg swizzled: jg ^ (d>>2)]
    __shared__ float Ps[64 * 64];  // [i][j]; reused as swizzled O-stage at end

    const int t  = threadIdx.x;
    const int tx = t & 15, ty = t >> 4;
    const int m0 = blockIdx.x * 64;
    const int bh = blockIdx.y;
    const int b  = bh >> 3, h = bh & 7;
    const float* qp = qkv + ((size_t)b * QKV_ROWS + h * 192) * N_TOK;
    const float* kp = qp + (size_t)HD * N_TOK;
    const float* vp = qp + (size_t)2 * HD * N_TOK;

    const int lr = t >> 4;          // load row base (0..15)
    const int lj = (t & 15) * 4;    // load col (float4)

    // stage Q tile: Qs[d][i]
    #pragma unroll
    for (int r = 0; r < 4; ++r) {
        int d = r * 16 + lr;
        *(float4*)&Qs[d * 64 + lj] = *(const float4*)&qp[(size_t)d * N_TOK + m0 + lj];
    }
    float m_run[4], l_run[4], o_acc[4][4];
    #pragma unroll
    for (int ii = 0; ii < 4; ++ii) {
        m_run[ii] = -1e30f; l_run[ii] = 0.f;
        for (int dd = 0; dd < 4; ++dd) o_acc[ii][dd] = 0.f;
    }
    __syncthreads();

    for (int kt = 0; kt < N_TOK / 64; ++kt) {
        const int n0 = kt * 64;
        __syncthreads();   // prior GEMM2 finished reading Ks/Vs/Ps
        #pragma unroll
        for (int r = 0; r < 4; ++r) {
            int d = r * 16 + lr;
            *(float4*)&Ks[d * 64 + lj] = *(const float4*)&kp[(size_t)d * N_TOK + n0 + lj];
            int g = (lj >> 2) ^ (d >> 2);   // column-group XOR swizzle
            *(float4*)&Vs[d * 64 + g * 4] = *(const float4*)&vp[(size_t)d * N_TOK + n0 + lj];
        }
        __syncthreads();

        // GEMM1: S[i][j] = sum_d Q[d][i] * K[d][j]
        float s[4][4] = {};
        #pragma unroll 8
        for (int kk = 0; kk < 64; ++kk) {
            float4 a  = *(const float4*)&Qs[kk * 64 + ty * 4];
            float4 bq = *(const float4*)&Ks[kk * 64 + tx * 4];
            s[0][0] += a.x * bq.x; s[0][1] += a.x * bq.y; s[0][2] += a.x * bq.z; s[0][3] += a.x * bq.w;
            s[1][0] += a.y * bq.x; s[1][1] += a.y * bq.y; s[1][2] += a.y * bq.z; s[1][3] += a.y * bq.w;
            s[2][0] += a.z * bq.x; s[2][1] += a.z * bq.y; s[2][2] += a.z * bq.z; s[2][3] += a.z * bq.w;
            s[3][0] += a.w * bq.x; s[3][1] += a.w * bq.y; s[3][2] += a.w * bq.z; s[3][3] += a.w * bq.w;
        }

        // online softmax per query row (replicated across the 16 tx lanes)
        #pragma unroll
        for (int ii = 0; ii < 4; ++ii) {
            float rm = fmaxf(fmaxf(s[ii][0], s[ii][1]), fmaxf(s[ii][2], s[ii][3]));
            #pragma unroll
            for (int off = 1; off < 16; off <<= 1) rm = fmaxf(rm, __shfl_xor(rm, off));
            float mn = fmaxf(m_run[ii], rm);
            float sc = __expf(m_run[ii] - mn);
            m_run[ii] = mn;
            float p0 = __expf(s[ii][0] - mn);
            float p1 = __expf(s[ii][1] - mn);
            float p2 = __expf(s[ii][2] - mn);
            float p3 = __expf(s[ii][3] - mn);
            float rs = p0 + p1 + p2 + p3;
            #pragma unroll
            for (int off = 1; off < 16; off <<= 1) rs += __shfl_xor(rs, off);
            l_run[ii] = l_run[ii] * sc + rs;
            #pragma unroll
            for (int dd = 0; dd < 4; ++dd) o_acc[ii][dd] *= sc;
            *(float4*)&Ps[(ty * 4 + ii) * 64 + tx * 4] = make_float4(p0, p1, p2, p3);
        }
        __syncthreads();

        // GEMM2: O[i][d] += sum_j P[i][j] * V[d][j]
        #pragma unroll 4
        for (int jg = 0; jg < 16; ++jg) {
            float4 pv[4], vv[4];
            #pragma unroll
            for (int ii = 0; ii < 4; ++ii) pv[ii] = *(const float4*)&Ps[(ty * 4 + ii) * 64 + jg * 4];
            #pragma unroll
            for (int dd = 0; dd < 4; ++dd) vv[dd] = *(const float4*)&Vs[(tx * 4 + dd) * 64 + ((jg ^ tx) << 2)];
            #pragma unroll
            for (int ii = 0; ii < 4; ++ii)
                #pragma unroll
                for (int dd = 0; dd < 4; ++dd)
                    o_acc[ii][dd] += pv[ii].x * vv[dd].x + pv[ii].y * vv[dd].y +
                                     pv[ii].z * vv[dd].z + pv[ii].w * vv[dd].w;
        }
    }

    // epilogue: normalize, stage to LDS (reuse Ps) for coalesced writes
    float inv[4];
    #pragma unroll
    for (int ii = 0; ii < 4; ++ii) inv[ii] = 1.0f / l_run[ii];
    __syncthreads();
    #pragma unroll
    for (int dd = 0; dd < 4; ++dd) {
        int d = tx * 4 + dd;
        *(float4*)&Ps[d * 64 + ((ty ^ tx) << 2)] =
            make_float4(o_acc[0][dd] * inv[0], o_acc[1][dd] * inv[1],
                        o_acc[2][dd] * inv[2], o_acc[3][dd] * inv[3]);
    }
    __syncthreads();
    float* outp = out + ((size_t)b * CH + h * HD) * N_TOK;
    #pragma unroll
    for (int r = 0; r < 4; ++r) {
        int d  = r * 16 + lr;
        int ig = t & 15;
        float4 val = *(const float4*)&Ps[d * 64 + ((ig ^ (d >> 2)) << 2)];
        *(float4*)&outp[(size_t)d * N_TOK + m0 + ig * 4] = val;
    }
}

extern "C" void kernel_launch(void* const* d_in, const int* in_sizes, int n_in,
                              void* d_out, int out_size, void* d_ws, size_t ws_size,
                              hipStream_t stream) {
    const float* x = (const float*)d_in[0];
    const float* w = (const float*)d_in[1];
    float* out = (float*)d_out;

    float* xds = (float*)d_ws;                               // 2*512*3136 floats
    float* qkv = xds + (size_t)2 * CH * N_TOK;               // 2*1536*3136 floats

    // 1) downsample
    k_downsample<<<dim3((2 * CH * N_TOK) / 256), dim3(256), 0, stream>>>(x, xds);
    // 2) qkv projection
    k_qkv_gemm<<<dim3(N_TOK / 64, QKV_ROWS / 64, 2), dim3(256), 0, stream>>>(w, xds, qkv);
    // 3) attention
    k_attn<<<dim3(N_TOK / 64, 16), dim3(256), 0, stream>>>(qkv, out);
}

// Round 6
// 255.282 us; speedup vs baseline: 4.2092x; 4.2092x over previous
//
#include <hip/hip_runtime.h>

#define N_TOK 3136   // 56*56
#define WOUT 56
#define CH 512
#define HD 64

typedef __attribute__((ext_vector_type(8))) short short8;
typedef __attribute__((ext_vector_type(4))) float f32x4;

__device__ inline unsigned short f2bf(float f) {
    unsigned u = __builtin_bit_cast(unsigned, f);
    unsigned r = u + 0x7FFFu + ((u >> 16) & 1u);
    return (unsigned short)(r >> 16);
}
__device__ inline float bf2f(unsigned short s) {
    unsigned u = ((unsigned)s) << 16;
    return __builtin_bit_cast(float, u);
}
__device__ inline unsigned pack2(float a, float b) {
    return (unsigned)f2bf(a) | ((unsigned)f2bf(b) << 16);
}

// ws layout (short elements)
#define WS_XH  0
#define WS_XL  3211264
#define WS_WB  6422528
#define WS_QTH 7208960
#define WS_QTL 10420224
#define WS_KTH 13631488
#define WS_KTL 16842752
#define WS_VW  20054016

// ---------- downsample + transpose + bf16 split: x(2,512,112,112) -> xT_hi/lo (2,3136,512) bf16 ----------
__global__ __launch_bounds__(256) void k_ds(const float* __restrict__ x,
                                            short* __restrict__ xh,
                                            short* __restrict__ xl) {
    __shared__ float tile[64 * 65];
    const int t = threadIdx.x, q = t >> 6, l = t & 63;
    const int n0 = blockIdx.x * 64, c0 = blockIdx.y * 64, b = blockIdx.z;
    #pragma unroll
    for (int r = 0; r < 16; ++r) {
        int c_l = q * 16 + r;
        int n = n0 + l;
        int hh = n / WOUT, ww = n - hh * WOUT;
        tile[c_l * 65 + l] =
            x[(((size_t)(b * CH + c0 + c_l)) * 112 + hh * 2) * 112 + ww * 2];
    }
    __syncthreads();
    #pragma unroll
    for (int r = 0; r < 16; ++r) {
        int n_l = q * 16 + r;
        float v = tile[l * 65 + n_l];
        unsigned short hi = f2bf(v);
        float lo = v - bf2f(hi);
        size_t base = ((size_t)b * N_TOK + n0 + n_l) * CH + c0 + l;
        xh[base] = (short)hi;
        xl[base] = (short)f2bf(lo);
    }
}

// ---------- w fp32 -> bf16 ----------
__global__ __launch_bounds__(256) void k_wcvt(const float* __restrict__ w, short* __restrict__ wb) {
    int i = blockIdx.x * 256 + threadIdx.x;   // 1536*512 = 3072*256
    wb[i] = (short)f2bf(w[i]);
}

// ---------- projection: qkv[o,n] = sum_c w[o,c] (xh+xl)[n,c] ----------
// q,k written token-major split-bf16 (hi+lo); v d-major bf16
__global__ __launch_bounds__(256) void k_proj(const short* __restrict__ wb,
                                              const short* __restrict__ xh,
                                              const short* __restrict__ xl,
                                              short* __restrict__ qTh,
                                              short* __restrict__ qTl,
                                              short* __restrict__ kTh,
                                              short* __restrict__ kTl,
                                              short* __restrict__ vW) {
    __shared__ __align__(16) short Wt[64 * 40];
    __shared__ __align__(16) short Xh[64 * 40];
    __shared__ __align__(16) short Xl[64 * 40];
    const int t = threadIdx.x;
    const int n0 = blockIdx.x * 64, o0 = blockIdx.y * 64, b = blockIdx.z;
    const int w = t >> 6, L = t & 63, lm = L & 15, g = L >> 4;
    const int wo = w >> 1, wn = w & 1;
    const int sr = t >> 2, sc = (t & 3) * 8;

    f32x4 acc[2][2] = {};
    for (int kc = 0; kc < 16; ++kc) {
        const int c0 = kc * 32;
        __syncthreads();
        *(short8*)&Wt[sr * 40 + sc] = *(const short8*)&wb[(size_t)(o0 + sr) * CH + c0 + sc];
        *(short8*)&Xh[sr * 40 + sc] = *(const short8*)&xh[((size_t)b * N_TOK + n0 + sr) * CH + c0 + sc];
        *(short8*)&Xl[sr * 40 + sc] = *(const short8*)&xl[((size_t)b * N_TOK + n0 + sr) * CH + c0 + sc];
        __syncthreads();
        short8 a0 = *(short8*)&Wt[(wo * 32 + lm) * 40 + g * 8];
        short8 a1 = *(short8*)&Wt[(wo * 32 + 16 + lm) * 40 + g * 8];
        short8 b0h = *(short8*)&Xh[(wn * 32 + lm) * 40 + g * 8];
        short8 b1h = *(short8*)&Xh[(wn * 32 + 16 + lm) * 40 + g * 8];
        short8 b0l = *(short8*)&Xl[(wn * 32 + lm) * 40 + g * 8];
        short8 b1l = *(short8*)&Xl[(wn * 32 + 16 + lm) * 40 + g * 8];
        acc[0][0] = __builtin_amdgcn_mfma_f32_16x16x32_bf16(a0, b0h, acc[0][0], 0, 0, 0);
        acc[0][0] = __builtin_amdgcn_mfma_f32_16x16x32_bf16(a0, b0l, acc[0][0], 0, 0, 0);
        acc[0][1] = __builtin_amdgcn_mfma_f32_16x16x32_bf16(a0, b1h, acc[0][1], 0, 0, 0);
        acc[0][1] = __builtin_amdgcn_mfma_f32_16x16x32_bf16(a0, b1l, acc[0][1], 0, 0, 0);
        acc[1][0] = __builtin_amdgcn_mfma_f32_16x16x32_bf16(a1, b0h, acc[1][0], 0, 0, 0);
        acc[1][0] = __builtin_amdgcn_mfma_f32_16x16x32_bf16(a1, b0l, acc[1][0], 0, 0, 0);
        acc[1][1] = __builtin_amdgcn_mfma_f32_16x16x32_bf16(a1, b1h, acc[1][1], 0, 0, 0);
        acc[1][1] = __builtin_amdgcn_mfma_f32_16x16x32_bf16(a1, b1l, acc[1][1], 0, 0, 0);
    }
    #pragma unroll
    for (int ot = 0; ot < 2; ++ot) {
        int obase = o0 + wo * 32 + ot * 16;
        int h = obase / 192;
        int typ = (obase / 64) % 3;
        int dbase = (wo * 32 + ot * 16) & 63;
        #pragma unroll
        for (int nt = 0; nt < 2; ++nt) {
            #pragma unroll
            for (int j = 0; j < 4; ++j) {
                int d = dbase + g * 4 + j;
                int n = n0 + wn * 32 + nt * 16 + lm;
                float val = acc[ot][nt][j];
                unsigned short hi = f2bf(val);
                float lo = val - bf2f(hi);
                size_t idxT = ((size_t)(b * 8 + h) * N_TOK + n) * HD + d;
                if (typ == 0) {
                    qTh[idxT] = (short)hi;
                    qTl[idxT] = (short)f2bf(lo);
                } else if (typ == 1) {
                    kTh[idxT] = (short)hi;
                    kTl[idxT] = (short)f2bf(lo);
                } else {
                    vW[((size_t)(b * 8 + h) * HD + d) * N_TOK + n] = (short)hi;
                }
            }
        }
    }
}

// ---------- flash attention, bf16 MFMA, split-bf16 QK^T ----------
// grid (49 m-tiles, 16 bh); 4 waves, 16 queries each; key chunks of 32
__global__ __launch_bounds__(256) void k_attn2(const short* __restrict__ qTh,
                                               const short* __restrict__ qTl,
                                               const short* __restrict__ kTh,
                                               const short* __restrict__ kTl,
                                               const short* __restrict__ vW,
                                               float* __restrict__ out) {
    __shared__ __align__(16) short Kh[32 * 72];   // [n][d] hi, 144B pitch
    __shared__ __align__(16) short Kl[32 * 72];   // [n][d] lo
    __shared__ __align__(16) short Vt[64 * 40];   // [d][n], 80B pitch
    __shared__ __align__(16) short Pl[4 * 16 * 40]; // per-wave P [m][n], 80B pitch

    const int t = threadIdx.x;
    const int w = t >> 6, L = t & 63, lm = L & 15, g = L >> 4;
    const int bh = blockIdx.y;
    const int mw = blockIdx.x * 64 + w * 16;       // wave's 16-query base

    // hoist Q fragments (B-operand): lane lm = query m, k = d
    const size_t qbase = ((size_t)bh * N_TOK + mw + lm) * HD;
    short8 qh0 = *(const short8*)&qTh[qbase + g * 8];
    short8 qh1 = *(const short8*)&qTh[qbase + 32 + g * 8];
    short8 ql0 = *(const short8*)&qTl[qbase + g * 8];
    short8 ql1 = *(const short8*)&qTl[qbase + 32 + g * 8];

    float m_run = -1e30f, l_run = 0.f;
    f32x4 o_acc[4] = {};

    const int kn = t >> 3, kc = (t & 7) * 8;   // K stage: 32 rows x 8 chunks
    const int vd = t >> 2, vc = (t & 3) * 8;   // V stage: 64 rows x 4 chunks

    for (int ch = 0; ch < N_TOK / 32; ++ch) {
        const int n0 = ch * 32;
        __syncthreads();
        *(short8*)&Kh[kn * 72 + kc] = *(const short8*)&kTh[((size_t)bh * N_TOK + n0 + kn) * HD + kc];
        *(short8*)&Kl[kn * 72 + kc] = *(const short8*)&kTl[((size_t)bh * N_TOK + n0 + kn) * HD + kc];
        *(short8*)&Vt[vd * 40 + vc] = *(const short8*)&vW[((size_t)bh * HD + vd) * N_TOK + n0 + vc];
        __syncthreads();

        // QK^T (swapped): S^T[n][m]; A = K rows, B = Q rows
        // S = Kh*Qh + Kh*Ql + Kl*Qh  (Kl*Ql dropped, ~2^-18 rel)
        f32x4 s0 = {}, s1 = {};
        {
            short8 ah = *(short8*)&Kh[lm * 72 + g * 8];
            short8 al = *(short8*)&Kl[lm * 72 + g * 8];
            s0 = __builtin_amdgcn_mfma_f32_16x16x32_bf16(ah, qh0, s0, 0, 0, 0);
            s0 = __builtin_amdgcn_mfma_f32_16x16x32_bf16(ah, ql0, s0, 0, 0, 0);
            s0 = __builtin_amdgcn_mfma_f32_16x16x32_bf16(al, qh0, s0, 0, 0, 0);
            ah = *(short8*)&Kh[lm * 72 + 32 + g * 8];
            al = *(short8*)&Kl[lm * 72 + 32 + g * 8];
            s0 = __builtin_amdgcn_mfma_f32_16x16x32_bf16(ah, qh1, s0, 0, 0, 0);
            s0 = __builtin_amdgcn_mfma_f32_16x16x32_bf16(ah, ql1, s0, 0, 0, 0);
            s0 = __builtin_amdgcn_mfma_f32_16x16x32_bf16(al, qh1, s0, 0, 0, 0);
            ah = *(short8*)&Kh[(16 + lm) * 72 + g * 8];
            al = *(short8*)&Kl[(16 + lm) * 72 + g * 8];
            s1 = __builtin_amdgcn_mfma_f32_16x16x32_bf16(ah, qh0, s1, 0, 0, 0);
            s1 = __builtin_amdgcn_mfma_f32_16x16x32_bf16(ah, ql0, s1, 0, 0, 0);
            s1 = __builtin_amdgcn_mfma_f32_16x16x32_bf16(al, qh0, s1, 0, 0, 0);
            ah = *(short8*)&Kh[(16 + lm) * 72 + 32 + g * 8];
            al = *(short8*)&Kl[(16 + lm) * 72 + 32 + g * 8];
            s1 = __builtin_amdgcn_mfma_f32_16x16x32_bf16(ah, qh1, s1, 0, 0, 0);
            s1 = __builtin_amdgcn_mfma_f32_16x16x32_bf16(ah, ql1, s1, 0, 0, 0);
            s1 = __builtin_amdgcn_mfma_f32_16x16x32_bf16(al, qh1, s1, 0, 0, 0);
        }
        // online softmax: lane owns query m = lm; 8 key-scores: n = 16*tile + 4g + j
        float p[8];
        p[0] = s0[0]; p[1] = s0[1]; p[2] = s0[2]; p[3] = s0[3];
        p[4] = s1[0]; p[5] = s1[1]; p[6] = s1[2]; p[7] = s1[3];
        float cmax = fmaxf(fmaxf(fmaxf(p[0], p[1]), fmaxf(p[2], p[3])),
                           fmaxf(fmaxf(p[4], p[5]), fmaxf(p[6], p[7])));
        cmax = fmaxf(cmax, __shfl_xor(cmax, 16));
        cmax = fmaxf(cmax, __shfl_xor(cmax, 32));
        float mnew = fmaxf(m_run, cmax);
        float alpha = __expf(m_run - mnew);
        m_run = mnew;
        float psum = 0.f;
        #pragma unroll
        for (int j = 0; j < 8; ++j) { p[j] = __expf(p[j] - mnew); psum += p[j]; }
        psum += __shfl_xor(psum, 16);
        psum += __shfl_xor(psum, 32);
        l_run = l_run * alpha + psum;
        #pragma unroll
        for (int dt = 0; dt < 4; ++dt) {
            o_acc[dt][0] *= alpha; o_acc[dt][1] *= alpha;
            o_acc[dt][2] *= alpha; o_acc[dt][3] *= alpha;
        }
        // pack P -> per-wave LDS [m][n]
        short* Pw = &Pl[w * 640];
        *(unsigned*)&Pw[lm * 40 + g * 4]          = pack2(p[0], p[1]);
        *(unsigned*)&Pw[lm * 40 + g * 4 + 2]      = pack2(p[2], p[3]);
        *(unsigned*)&Pw[lm * 40 + 16 + g * 4]     = pack2(p[4], p[5]);
        *(unsigned*)&Pw[lm * 40 + 16 + g * 4 + 2] = pack2(p[6], p[7]);
        __syncthreads();

        // PV: D[d][m] += V[d][n] * P^T[n][m]; A = V rows, B = P rows (m = lm)
        short8 bp = *(short8*)&Pw[lm * 40 + g * 8];
        #pragma unroll
        for (int dt = 0; dt < 4; ++dt) {
            short8 av = *(short8*)&Vt[(dt * 16 + lm) * 40 + g * 8];
            o_acc[dt] = __builtin_amdgcn_mfma_f32_16x16x32_bf16(av, bp, o_acc[dt], 0, 0, 0);
        }
    }

    float inv = 1.0f / l_run;
    #pragma unroll
    for (int dt = 0; dt < 4; ++dt)
        #pragma unroll
        for (int j = 0; j < 4; ++j)
            out[((size_t)bh * HD + dt * 16 + g * 4 + j) * N_TOK + mw + lm] = o_acc[dt][j] * inv;
}

extern "C" void kernel_launch(void* const* d_in, const int* in_sizes, int n_in,
                              void* d_out, int out_size, void* d_ws, size_t ws_size,
                              hipStream_t stream) {
    const float* x = (const float*)d_in[0];
    const float* wq = (const float*)d_in[1];
    float* out = (float*)d_out;
    short* ws = (short*)d_ws;

    short* xh  = ws + WS_XH;
    short* xl  = ws + WS_XL;
    short* wb  = ws + WS_WB;
    short* qTh = ws + WS_QTH;
    short* qTl = ws + WS_QTL;
    short* kTh = ws + WS_KTH;
    short* kTl = ws + WS_KTL;
    short* vW  = ws + WS_VW;

    k_ds<<<dim3(49, 8, 2), 256, 0, stream>>>(x, xh, xl);
    k_wcvt<<<dim3(3072), 256, 0, stream>>>(wq, wb);
    k_proj<<<dim3(49, 24, 2), 256, 0, stream>>>(wb, xh, xl, qTh, qTl, kTh, kTl, vW);
    k_attn2<<<dim3(49, 16), 256, 0, stream>>>(qTh, qTl, kTh, kTl, vW, out);
}

// Round 7
// 175.366 us; speedup vs baseline: 6.1274x; 1.4557x over previous
//
#include <hip/hip_runtime.h>

#define N_TOK 3136   // 56*56
#define WOUT 56
#define CH 512
#define HD 64
#define NCH 49       // 3136 / 64 key chunks

typedef _Float16 h4 __attribute__((ext_vector_type(4)));
typedef _Float16 h8 __attribute__((ext_vector_type(8)));
typedef float f32x4 __attribute__((ext_vector_type(4)));

// ws offsets in f16 elements
#define WS_XH 0
#define WS_XL 3211264
#define WS_WF 6422528
#define WS_QT 7208960
#define WS_KT 10420224
#define WS_VW 13631488

// ---------- downsample + transpose + f16 split: x(2,512,112,112) -> xT hi/lo (2,3136,512) ----------
__global__ __launch_bounds__(256) void k_ds(const float* __restrict__ x,
                                            _Float16* __restrict__ xh,
                                            _Float16* __restrict__ xl) {
    __shared__ float tile[64 * 65];
    const int t = threadIdx.x, q = t >> 6, l = t & 63;
    const int n0 = blockIdx.x * 64, c0 = blockIdx.y * 64, b = blockIdx.z;
    #pragma unroll
    for (int r = 0; r < 16; ++r) {
        int c_l = q * 16 + r;
        int n = n0 + l;
        int hh = n / WOUT, ww = n - hh * WOUT;
        tile[c_l * 65 + l] =
            x[(((size_t)(b * CH + c0 + c_l)) * 112 + hh * 2) * 112 + ww * 2];
    }
    __syncthreads();
    #pragma unroll
    for (int r = 0; r < 16; ++r) {
        int n_l = q * 16 + r;
        float v = tile[l * 65 + n_l];
        _Float16 hi = (_Float16)v;
        _Float16 lo = (_Float16)(v - (float)hi);
        size_t base = ((size_t)b * N_TOK + n0 + n_l) * CH + c0 + l;
        xh[base] = hi;
        xl[base] = lo;
    }
}

// ---------- w fp32 -> f16 ----------
__global__ __launch_bounds__(256) void k_wcvt(const float* __restrict__ w, _Float16* __restrict__ wf) {
    int i = blockIdx.x * 256 + threadIdx.x;   // 1536*512 = 3072*256
    wf[i] = (_Float16)w[i];
}

// ---------- projection: qkv[o,n] = sum_c w[o,c] (xh+xl)[n,c]; q,k token-major f16, v d-major f16 ----------
__global__ __launch_bounds__(256) void k_proj(const _Float16* __restrict__ wf,
                                              const _Float16* __restrict__ xh,
                                              const _Float16* __restrict__ xl,
                                              _Float16* __restrict__ qT,
                                              _Float16* __restrict__ kT,
                                              _Float16* __restrict__ vW) {
    __shared__ __align__(16) _Float16 Wt[64 * 40];
    __shared__ __align__(16) _Float16 Xh[64 * 40];
    __shared__ __align__(16) _Float16 Xl[64 * 40];
    const int t = threadIdx.x;
    const int n0 = blockIdx.x * 64, o0 = blockIdx.y * 64, b = blockIdx.z;
    const int w = t >> 6, L = t & 63, lm = L & 15, g = L >> 4;
    const int wo = w >> 1, wn = w & 1;
    const int sr = t >> 2, sc = (t & 3) * 8;

    f32x4 acc[2][2] = {};
    for (int kc = 0; kc < 16; ++kc) {
        const int c0 = kc * 32;
        __syncthreads();
        *(h8*)&Wt[sr * 40 + sc] = *(const h8*)&wf[(size_t)(o0 + sr) * CH + c0 + sc];
        *(h8*)&Xh[sr * 40 + sc] = *(const h8*)&xh[((size_t)b * N_TOK + n0 + sr) * CH + c0 + sc];
        *(h8*)&Xl[sr * 40 + sc] = *(const h8*)&xl[((size_t)b * N_TOK + n0 + sr) * CH + c0 + sc];
        __syncthreads();
        h8 a0 = *(h8*)&Wt[(wo * 32 + lm) * 40 + g * 8];
        h8 a1 = *(h8*)&Wt[(wo * 32 + 16 + lm) * 40 + g * 8];
        h8 b0h = *(h8*)&Xh[(wn * 32 + lm) * 40 + g * 8];
        h8 b1h = *(h8*)&Xh[(wn * 32 + 16 + lm) * 40 + g * 8];
        h8 b0l = *(h8*)&Xl[(wn * 32 + lm) * 40 + g * 8];
        h8 b1l = *(h8*)&Xl[(wn * 32 + 16 + lm) * 40 + g * 8];
        acc[0][0] = __builtin_amdgcn_mfma_f32_16x16x32_f16(a0, b0h, acc[0][0], 0, 0, 0);
        acc[0][0] = __builtin_amdgcn_mfma_f32_16x16x32_f16(a0, b0l, acc[0][0], 0, 0, 0);
        acc[0][1] = __builtin_amdgcn_mfma_f32_16x16x32_f16(a0, b1h, acc[0][1], 0, 0, 0);
        acc[0][1] = __builtin_amdgcn_mfma_f32_16x16x32_f16(a0, b1l, acc[0][1], 0, 0, 0);
        acc[1][0] = __builtin_amdgcn_mfma_f32_16x16x32_f16(a1, b0h, acc[1][0], 0, 0, 0);
        acc[1][0] = __builtin_amdgcn_mfma_f32_16x16x32_f16(a1, b0l, acc[1][0], 0, 0, 0);
        acc[1][1] = __builtin_amdgcn_mfma_f32_16x16x32_f16(a1, b1h, acc[1][1], 0, 0, 0);
        acc[1][1] = __builtin_amdgcn_mfma_f32_16x16x32_f16(a1, b1l, acc[1][1], 0, 0, 0);
    }
    #pragma unroll
    for (int ot = 0; ot < 2; ++ot) {
        int obase = o0 + wo * 32 + ot * 16;
        int h = obase / 192;
        int typ = (obase / 64) % 3;
        int dbase = (wo * 32 + ot * 16) & 63;
        #pragma unroll
        for (int nt = 0; nt < 2; ++nt) {
            int n = n0 + wn * 32 + nt * 16 + lm;
            f32x4 a = acc[ot][nt];
            if (typ == 2) {
                #pragma unroll
                for (int j = 0; j < 4; ++j)
                    vW[((size_t)(b * 8 + h) * HD + dbase + g * 4 + j) * N_TOK + n] = (_Float16)a[j];
            } else {
                h4 hv = {(_Float16)a[0], (_Float16)a[1], (_Float16)a[2], (_Float16)a[3]};
                _Float16* dst = (typ == 0) ? qT : kT;
                *(h4*)&dst[((size_t)(b * 8 + h) * N_TOK + n) * HD + dbase + g * 4] = hv;
            }
        }
    }
}

// ---------- flash attention, f16 MFMA, KVBLK=64, double-buffered LDS, 1 barrier/chunk ----------
__global__ __launch_bounds__(256) void k_attn3(const _Float16* __restrict__ qT,
                                               const _Float16* __restrict__ kT,
                                               const _Float16* __restrict__ vW,
                                               float* __restrict__ out) {
    __shared__ __align__(16) _Float16 Ks[2][64 * 72];   // [n][d], 144B pitch
    __shared__ __align__(16) _Float16 Vs[2][64 * 72];   // [d][n], 144B pitch
    __shared__ __align__(16) _Float16 Ps[4][16 * 72];   // per-wave P [m][n]

    const int t = threadIdx.x;
    const int w = t >> 6, L = t & 63, lm = L & 15, g = L >> 4;
    const int bh = blockIdx.y;
    const int mw = blockIdx.x * 64 + w * 16;

    // hoist Q fragments (B-operand): lane lm = query m
    const size_t qb = ((size_t)bh * N_TOK + mw + lm) * HD;
    h8 qf0 = *(const h8*)&qT[qb + g * 8];
    h8 qf1 = *(const h8*)&qT[qb + 32 + g * 8];

    const int srow = t >> 3, scol = (t & 7) * 8;   // staging: 2 rows of 64 per thread
    float m_run = -1e30f, l_run = 0.f;
    f32x4 o_acc[4] = {};
    _Float16* Pw = &Ps[w][0];

    // prologue: stage chunk 0
    {
        h8 a = *(const h8*)&kT[((size_t)bh * N_TOK + srow) * HD + scol];
        h8 bq = *(const h8*)&kT[((size_t)bh * N_TOK + srow + 32) * HD + scol];
        h8 c = *(const h8*)&vW[((size_t)bh * HD + srow) * N_TOK + scol];
        h8 d = *(const h8*)&vW[((size_t)bh * HD + srow + 32) * N_TOK + scol];
        *(h8*)&Ks[0][srow * 72 + scol] = a;
        *(h8*)&Ks[0][(srow + 32) * 72 + scol] = bq;
        *(h8*)&Vs[0][srow * 72 + scol] = c;
        *(h8*)&Vs[0][(srow + 32) * 72 + scol] = d;
    }
    __syncthreads();

    int cur = 0;
    for (int ch = 0; ch < NCH; ++ch) {
        const bool pf = (ch + 1 < NCH);
        const int nn = (ch + 1) * 64;
        h8 pk0, pk1, pv0, pv1;
        if (pf) {   // prefetch next chunk into registers (latency hidden under compute)
            pk0 = *(const h8*)&kT[((size_t)bh * N_TOK + nn + srow) * HD + scol];
            pk1 = *(const h8*)&kT[((size_t)bh * N_TOK + nn + srow + 32) * HD + scol];
            pv0 = *(const h8*)&vW[((size_t)bh * HD + srow) * N_TOK + nn + scol];
            pv1 = *(const h8*)&vW[((size_t)bh * HD + srow + 32) * N_TOK + nn + scol];
        }
        const _Float16* Kc = &Ks[cur][0];
        const _Float16* Vc = &Vs[cur][0];

        // QK^T (swapped): A = K rows, B = Q; S^T tile col = query (lm), row = key
        f32x4 s[4] = {};
        #pragma unroll
        for (int kt = 0; kt < 4; ++kt) {
            h8 a0 = *(const h8*)&Kc[(kt * 16 + lm) * 72 + g * 8];
            h8 a1 = *(const h8*)&Kc[(kt * 16 + lm) * 72 + 32 + g * 8];
            s[kt] = __builtin_amdgcn_mfma_f32_16x16x32_f16(a0, qf0, s[kt], 0, 0, 0);
            s[kt] = __builtin_amdgcn_mfma_f32_16x16x32_f16(a1, qf1, s[kt], 0, 0, 0);
        }

        // online softmax: lane owns query m = lm; 16 key-scores n = kt*16 + g*4 + j
        float cmax = -1e30f;
        #pragma unroll
        for (int kt = 0; kt < 4; ++kt)
            #pragma unroll
            for (int j = 0; j < 4; ++j) cmax = fmaxf(cmax, s[kt][j]);
        cmax = fmaxf(cmax, __shfl_xor(cmax, 16));
        cmax = fmaxf(cmax, __shfl_xor(cmax, 32));
        float mnew = fmaxf(m_run, cmax);
        float alpha = __expf(m_run - mnew);
        m_run = mnew;
        float psum = 0.f;
        #pragma unroll
        for (int kt = 0; kt < 4; ++kt) {
            float p0 = __expf(s[kt][0] - mnew);
            float p1 = __expf(s[kt][1] - mnew);
            float p2 = __expf(s[kt][2] - mnew);
            float p3 = __expf(s[kt][3] - mnew);
            psum += (p0 + p1) + (p2 + p3);
            h4 hv = {(_Float16)p0, (_Float16)p1, (_Float16)p2, (_Float16)p3};
            *(h4*)&Pw[lm * 72 + kt * 16 + g * 4] = hv;
        }
        psum += __shfl_xor(psum, 16);
        psum += __shfl_xor(psum, 32);
        l_run = l_run * alpha + psum;
        #pragma unroll
        for (int dt = 0; dt < 4; ++dt) {
            o_acc[dt][0] *= alpha; o_acc[dt][1] *= alpha;
            o_acc[dt][2] *= alpha; o_acc[dt][3] *= alpha;
        }

        // within-wave LDS write->read ordering (DS ops are in-order per wave)
        asm volatile("s_waitcnt lgkmcnt(0)" ::: "memory");

        // PV: A = V rows (d), B = P rows (m = lm)
        h8 bp0 = *(const h8*)&Pw[lm * 72 + g * 8];
        h8 bp1 = *(const h8*)&Pw[lm * 72 + 32 + g * 8];
        #pragma unroll
        for (int dt = 0; dt < 4; ++dt) {
            h8 av0 = *(const h8*)&Vc[(dt * 16 + lm) * 72 + g * 8];
            h8 av1 = *(const h8*)&Vc[(dt * 16 + lm) * 72 + 32 + g * 8];
            o_acc[dt] = __builtin_amdgcn_mfma_f32_16x16x32_f16(av0, bp0, o_acc[dt], 0, 0, 0);
            o_acc[dt] = __builtin_amdgcn_mfma_f32_16x16x32_f16(av1, bp1, o_acc[dt], 0, 0, 0);
        }

        if (pf) {
            const int nb = cur ^ 1;
            *(h8*)&Ks[nb][srow * 72 + scol] = pk0;
            *(h8*)&Ks[nb][(srow + 32) * 72 + scol] = pk1;
            *(h8*)&Vs[nb][srow * 72 + scol] = pv0;
            *(h8*)&Vs[nb][(srow + 32) * 72 + scol] = pv1;
            __syncthreads();   // next buffer complete before anyone reads it
            cur = nb;
        }
    }

    float inv = 1.0f / l_run;
    #pragma unroll
    for (int dt = 0; dt < 4; ++dt)
        #pragma unroll
        for (int j = 0; j < 4; ++j)
            out[((size_t)bh * HD + dt * 16 + g * 4 + j) * N_TOK + mw + lm] = o_acc[dt][j] * inv;
}

extern "C" void kernel_launch(void* const* d_in, const int* in_sizes, int n_in,
                              void* d_out, int out_size, void* d_ws, size_t ws_size,
                              hipStream_t stream) {
    const float* x = (const float*)d_in[0];
    const float* wq = (const float*)d_in[1];
    float* out = (float*)d_out;
    _Float16* ws = (_Float16*)d_ws;

    _Float16* xh = ws + WS_XH;
    _Float16* xl = ws + WS_XL;
    _Float16* wf = ws + WS_WF;
    _Float16* qT = ws + WS_QT;
    _Float16* kT = ws + WS_KT;
    _Float16* vW = ws + WS_VW;

    k_ds<<<dim3(49, 8, 2), 256, 0, stream>>>(x, xh, xl);
    k_wcvt<<<dim3(3072), 256, 0, stream>>>(wq, wf);
    k_proj<<<dim3(49, 24, 2), 256, 0, stream>>>(wf, xh, xl, qT, kT, vW);
    k_attn3<<<dim3(49, 16), 256, 0, stream>>>(qT, kT, vW, out);
}

// Round 9
// 162.353 us; speedup vs baseline: 6.6185x; 1.0802x over previous
//
#include <hip/hip_runtime.h>

#define N_TOK 3136   // 56*56
#define WOUT 56
#define CH 512
#define HD 64
#define NCH 49       // 3136 / 64 key chunks

typedef _Float16 h4 __attribute__((ext_vector_type(4)));
typedef _Float16 h8 __attribute__((ext_vector_type(8)));
typedef float f32x4 __attribute__((ext_vector_type(4)));
typedef float f32x16 __attribute__((ext_vector_type(16)));
typedef unsigned u32x2 __attribute__((ext_vector_type(2)));
typedef unsigned u32x4 __attribute__((ext_vector_type(4)));

// ws offsets in f16 elements
#define WS_XH 0
#define WS_XL 3211264
#define WS_WF 6422528
#define WS_QT 7208960
#define WS_KT 10420224
#define WS_VW 13631488

__device__ inline unsigned pkh(float a, float b) {
    return __builtin_bit_cast(unsigned, __builtin_amdgcn_cvt_pkrtz(a, b));
}
// swap: lanes>=32 of a  <->  lanes<32 of b
__device__ inline void plswap(unsigned& a, unsigned& b) {
#if __has_builtin(__builtin_amdgcn_permlane32_swap)
    u32x2 r = __builtin_amdgcn_permlane32_swap(a, b, false, false);
    a = r.x; b = r.y;
#else
    unsigned a2 = (unsigned)__shfl_xor((int)a, 32);
    unsigned b2 = (unsigned)__shfl_xor((int)b, 32);
    bool hi = (threadIdx.x & 63) >= 32;
    unsigned na = hi ? b2 : a;
    unsigned nb = hi ? b : a2;
    a = na; b = nb;
#endif
}

// ---------- downsample + transpose + f16 split ----------
__global__ __launch_bounds__(256) void k_ds(const float* __restrict__ x,
                                            _Float16* __restrict__ xh,
                                            _Float16* __restrict__ xl) {
    __shared__ float tile[64 * 65];
    const int t = threadIdx.x, q = t >> 6, l = t & 63;
    const int n0 = blockIdx.x * 64, c0 = blockIdx.y * 64, b = blockIdx.z;
    #pragma unroll
    for (int r = 0; r < 16; ++r) {
        int c_l = q * 16 + r;
        int n = n0 + l;
        int hh = n / WOUT, ww = n - hh * WOUT;
        tile[c_l * 65 + l] =
            x[(((size_t)(b * CH + c0 + c_l)) * 112 + hh * 2) * 112 + ww * 2];
    }
    __syncthreads();
    #pragma unroll
    for (int r = 0; r < 16; ++r) {
        int n_l = q * 16 + r;
        float v = tile[l * 65 + n_l];
        _Float16 hi = (_Float16)v;
        _Float16 lo = (_Float16)(v - (float)hi);
        size_t base = ((size_t)b * N_TOK + n0 + n_l) * CH + c0 + l;
        xh[base] = hi;
        xl[base] = lo;
    }
}

__global__ __launch_bounds__(256) void k_wcvt(const float* __restrict__ w, _Float16* __restrict__ wf) {
    int i = blockIdx.x * 256 + threadIdx.x;
    wf[i] = (_Float16)w[i];
}

// ---------- projection (unchanged from round 7) ----------
__global__ __launch_bounds__(256) void k_proj(const _Float16* __restrict__ wf,
                                              const _Float16* __restrict__ xh,
                                              const _Float16* __restrict__ xl,
                                              _Float16* __restrict__ qT,
                                              _Float16* __restrict__ kT,
                                              _Float16* __restrict__ vW) {
    __shared__ __align__(16) _Float16 Wt[64 * 40];
    __shared__ __align__(16) _Float16 Xh[64 * 40];
    __shared__ __align__(16) _Float16 Xl[64 * 40];
    const int t = threadIdx.x;
    const int n0 = blockIdx.x * 64, o0 = blockIdx.y * 64, b = blockIdx.z;
    const int w = t >> 6, L = t & 63, lm = L & 15, g = L >> 4;
    const int wo = w >> 1, wn = w & 1;
    const int sr = t >> 2, sc = (t & 3) * 8;

    f32x4 acc[2][2] = {};
    for (int kc = 0; kc < 16; ++kc) {
        const int c0 = kc * 32;
        __syncthreads();
        *(h8*)&Wt[sr * 40 + sc] = *(const h8*)&wf[(size_t)(o0 + sr) * CH + c0 + sc];
        *(h8*)&Xh[sr * 40 + sc] = *(const h8*)&xh[((size_t)b * N_TOK + n0 + sr) * CH + c0 + sc];
        *(h8*)&Xl[sr * 40 + sc] = *(const h8*)&xl[((size_t)b * N_TOK + n0 + sr) * CH + c0 + sc];
        __syncthreads();
        h8 a0 = *(h8*)&Wt[(wo * 32 + lm) * 40 + g * 8];
        h8 a1 = *(h8*)&Wt[(wo * 32 + 16 + lm) * 40 + g * 8];
        h8 b0h = *(h8*)&Xh[(wn * 32 + lm) * 40 + g * 8];
        h8 b1h = *(h8*)&Xh[(wn * 32 + 16 + lm) * 40 + g * 8];
        h8 b0l = *(h8*)&Xl[(wn * 32 + lm) * 40 + g * 8];
        h8 b1l = *(h8*)&Xl[(wn * 32 + 16 + lm) * 40 + g * 8];
        acc[0][0] = __builtin_amdgcn_mfma_f32_16x16x32_f16(a0, b0h, acc[0][0], 0, 0, 0);
        acc[0][0] = __builtin_amdgcn_mfma_f32_16x16x32_f16(a0, b0l, acc[0][0], 0, 0, 0);
        acc[0][1] = __builtin_amdgcn_mfma_f32_16x16x32_f16(a0, b1h, acc[0][1], 0, 0, 0);
        acc[0][1] = __builtin_amdgcn_mfma_f32_16x16x32_f16(a0, b1l, acc[0][1], 0, 0, 0);
        acc[1][0] = __builtin_amdgcn_mfma_f32_16x16x32_f16(a1, b0h, acc[1][0], 0, 0, 0);
        acc[1][0] = __builtin_amdgcn_mfma_f32_16x16x32_f16(a1, b0l, acc[1][0], 0, 0, 0);
        acc[1][1] = __builtin_amdgcn_mfma_f32_16x16x32_f16(a1, b1h, acc[1][1], 0, 0, 0);
        acc[1][1] = __builtin_amdgcn_mfma_f32_16x16x32_f16(a1, b1l, acc[1][1], 0, 0, 0);
    }
    #pragma unroll
    for (int ot = 0; ot < 2; ++ot) {
        int obase = o0 + wo * 32 + ot * 16;
        int h = obase / 192;
        int typ = (obase / 64) % 3;
        int dbase = (wo * 32 + ot * 16) & 63;
        #pragma unroll
        for (int nt = 0; nt < 2; ++nt) {
            int n = n0 + wn * 32 + nt * 16 + lm;
            f32x4 a = acc[ot][nt];
            if (typ == 2) {
                #pragma unroll
                for (int j = 0; j < 4; ++j)
                    vW[((size_t)(b * 8 + h) * HD + dbase + g * 4 + j) * N_TOK + n] = (_Float16)a[j];
            } else {
                h4 hv = {(_Float16)a[0], (_Float16)a[1], (_Float16)a[2], (_Float16)a[3]};
                _Float16* dst = (typ == 0) ? qT : kT;
                *(h4*)&dst[((size_t)(b * 8 + h) * N_TOK + n) * HD + dbase + g * 4] = hv;
            }
        }
    }
}

// ---------- flash attention: 32x32x16 MFMA, in-register P, 2 waves x 32 queries ----------
__global__ __launch_bounds__(128) void k_attn4(const _Float16* __restrict__ qT,
                                               const _Float16* __restrict__ kT,
                                               const _Float16* __restrict__ vW,
                                               float* __restrict__ out) {
    __shared__ __align__(16) _Float16 Ks[2][64 * 72];   // [n][d], pitch 72 halves
    __shared__ __align__(16) _Float16 Vs[2][64 * 72];   // [d][n], pitch 72

    const int t = threadIdx.x;
    const int w = t >> 6, L = t & 63, lm = L & 31, hi = L >> 5;

    // bijective chunked XCD swizzle: 784 blocks = 8 XCDs x 98; 98 = 2 full bh groups
    const int lin = blockIdx.x + 49 * blockIdx.y;
    const int nl = (lin & 7) * 98 + (lin >> 3);
    const int bh = nl / 49;
    const int mw = (nl % 49) * 64 + w * 32;

    // hoist Q (B-operand): lane: query col = lm, k-slice = hi*8
    const size_t qb = ((size_t)bh * N_TOK + mw + lm) * HD;
    h8 qf[4];
    #pragma unroll
    for (int ks = 0; ks < 4; ++ks) qf[ks] = *(const h8*)&qT[qb + ks * 16 + hi * 8];

    const int sr = t >> 1;              // staging row 0..63
    const int sci = (t & 1) * 4;        // 4 x 16B chunks per thread
    const size_t kgb = (size_t)bh * N_TOK * HD;
    const size_t vgb = (size_t)bh * HD * N_TOK;

    float m_run = -1e30f, l_run = 0.f;
    f32x16 o_acc[2] = {};

    // prologue: stage chunk 0
    #pragma unroll
    for (int i = 0; i < 4; ++i) {
        *(h8*)&Ks[0][sr * 72 + (sci + i) * 8] = *(const h8*)&kT[kgb + (size_t)sr * HD + (sci + i) * 8];
        *(h8*)&Vs[0][sr * 72 + (sci + i) * 8] = *(const h8*)&vW[vgb + (size_t)sr * N_TOK + (sci + i) * 8];
    }
    __syncthreads();

    int cur = 0;
    for (int ch = 0; ch < NCH; ++ch) {
        const bool pf = (ch + 1 < NCH);
        const int nn = (ch + 1) * 64;
        h8 pk[4], pv[4];
        if (pf) {
            #pragma unroll
            for (int i = 0; i < 4; ++i) {
                pk[i] = *(const h8*)&kT[kgb + (size_t)(nn + sr) * HD + (sci + i) * 8];
                pv[i] = *(const h8*)&vW[vgb + (size_t)sr * N_TOK + nn + (sci + i) * 8];
            }
        }
        const _Float16* Kc = &Ks[cur][0];
        const _Float16* Vc = &Vs[cur][0];

        // QK^T (swapped): A = K rows (keys), B = Q; D[key][query]
        f32x16 s0 = {}, s1 = {};
        __builtin_amdgcn_s_setprio(1);
        #pragma unroll
        for (int ks = 0; ks < 4; ++ks) {
            h8 a0 = *(const h8*)&Kc[(lm) * 72 + ks * 16 + hi * 8];
            h8 a1 = *(const h8*)&Kc[(32 + lm) * 72 + ks * 16 + hi * 8];
            s0 = __builtin_amdgcn_mfma_f32_32x32x16_f16(a0, qf[ks], s0, 0, 0, 0);
            s1 = __builtin_amdgcn_mfma_f32_32x32x16_f16(a1, qf[ks], s1, 0, 0, 0);
        }
        __builtin_amdgcn_s_setprio(0);

        // online softmax: lane owns query m = lm (paired with lane^32)
        float cmax = -1e30f;
        #pragma unroll
        for (int r = 0; r < 16; ++r) cmax = fmaxf(cmax, fmaxf(s0[r], s1[r]));
        cmax = fmaxf(cmax, __shfl_xor(cmax, 32));
        float mnew = fmaxf(m_run, cmax);
        float alpha = __expf(m_run - mnew);
        m_run = mnew;
        float p[2][16];
        float psum = 0.f;
        #pragma unroll
        for (int r = 0; r < 16; ++r) {
            p[0][r] = __expf(s0[r] - mnew);
            p[1][r] = __expf(s1[r] - mnew);
            psum += p[0][r] + p[1][r];
        }
        psum += __shfl_xor(psum, 32);
        l_run = l_run * alpha + psum;
        #pragma unroll
        for (int r = 0; r < 16; ++r) { o_acc[0][r] *= alpha; o_acc[1][r] *= alpha; }

        // P -> B-operand fragments in-register (cvt_pkrtz + permlane32_swap)
        h8 pfrag[4];
        #pragma unroll
        for (int kt = 0; kt < 2; ++kt) {
            #pragma unroll
            for (int half = 0; half < 2; ++half) {
                const int b0 = half * 8;
                unsigned w01 = pkh(p[kt][b0 + 0], p[kt][b0 + 1]);
                unsigned w23 = pkh(p[kt][b0 + 2], p[kt][b0 + 3]);
                unsigned w45 = pkh(p[kt][b0 + 4], p[kt][b0 + 5]);
                unsigned w67 = pkh(p[kt][b0 + 6], p[kt][b0 + 7]);
                plswap(w01, w45);
                plswap(w23, w67);
                u32x4 uu = {w01, w23, w45, w67};
                pfrag[kt * 2 + half] = __builtin_bit_cast(h8, uu);
            }
        }

        // PV: A = V rows (d), B = P; D[d][query]
        __builtin_amdgcn_s_setprio(1);
        #pragma unroll
        for (int ns = 0; ns < 4; ++ns) {
            h8 av0 = *(const h8*)&Vc[(lm) * 72 + ns * 16 + hi * 8];
            h8 av1 = *(const h8*)&Vc[(32 + lm) * 72 + ns * 16 + hi * 8];
            o_acc[0] = __builtin_amdgcn_mfma_f32_32x32x16_f16(av0, pfrag[ns], o_acc[0], 0, 0, 0);
            o_acc[1] = __builtin_amdgcn_mfma_f32_32x32x16_f16(av1, pfrag[ns], o_acc[1], 0, 0, 0);
        }
        __builtin_amdgcn_s_setprio(0);

        if (pf) {
            const int nb = cur ^ 1;
            #pragma unroll
            for (int i = 0; i < 4; ++i) {
                *(h8*)&Ks[nb][sr * 72 + (sci + i) * 8] = pk[i];
                *(h8*)&Vs[nb][sr * 72 + (sci + i) * 8] = pv[i];
            }
            __syncthreads();
            cur = nb;
        }
    }

    const float inv = 1.0f / l_run;
    #pragma unroll
    for (int dt = 0; dt < 2; ++dt)
        #pragma unroll
        for (int r = 0; r < 16; ++r) {
            int d = dt * 32 + (r & 3) + 8 * (r >> 2) + 4 * hi;
            out[((size_t)bh * HD + d) * N_TOK + mw + lm] = o_acc[dt][r] * inv;
        }
}

extern "C" void kernel_launch(void* const* d_in, const int* in_sizes, int n_in,
                              void* d_out, int out_size, void* d_ws, size_t ws_size,
                              hipStream_t stream) {
    const float* x = (const float*)d_in[0];
    const float* wq = (const float*)d_in[1];
    float* out = (float*)d_out;
    _Float16* ws = (_Float16*)d_ws;

    _Float16* xh = ws + WS_XH;
    _Float16* xl = ws + WS_XL;
    _Float16* wf = ws + WS_WF;
    _Float16* qT = ws + WS_QT;
    _Float16* kT = ws + WS_KT;
    _Float16* vW = ws + WS_VW;

    k_ds<<<dim3(49, 8, 2), 256, 0, stream>>>(x, xh, xl);
    k_wcvt<<<dim3(3072), 256, 0, stream>>>(wq, wf);
    k_proj<<<dim3(49, 24, 2), 256, 0, stream>>>(wf, xh, xl, qT, kT, vW);
    k_attn4<<<dim3(49, 16), 128, 0, stream>>>(qT, kT, vW, out);
}